// Round 3
// baseline (482.303 us; speedup 1.0000x reference)
//
#include <hip/hip_runtime.h>

typedef short s16x8 __attribute__((ext_vector_type(8)));
typedef float f32x4 __attribute__((ext_vector_type(4)));
typedef unsigned int u32;

#define DEV static __device__ __forceinline__

DEV unsigned short f2bf(float x){
  u32 u = __builtin_bit_cast(u32, x);
  return (unsigned short)((u + 0x7FFFu + ((u >> 16) & 1u)) >> 16);
}
DEV float bf2f(unsigned short h){ u32 u = ((u32)h) << 16; return __builtin_bit_cast(float, u); }
DEV u32 pack2(float a, float b){ return (u32)f2bf(a) | ((u32)f2bf(b) << 16); }

DEV void gld16(const void* g, void* l){
  __builtin_amdgcn_global_load_lds((const __attribute__((address_space(1))) u32*)g,
                                   (__attribute__((address_space(3))) u32*)l, 16, 0, 0);
}

// ---------------- transpose f32 -> bf16 (tiny matrices) ----------------
__global__ void k_transpose_bf16(const float* __restrict__ src,
                                 unsigned short* __restrict__ dst, int R, int C){
  int idx = blockIdx.x * 256 + threadIdx.x;
  if (idx >= R * C) return;
  int r = idx / C, c = idx % C;
  dst[(size_t)c * R + r] = f2bf(src[idx]);
}

// ------- staging helpers -------
// bf16 operand: global_load_lds(16B), LDS linear dest; swizzle applied on the
// GLOBAL source k-chunk (rule 21 / m173): LDS slot s of row r holds source
// chunk s ^ (r & SLM); ds_read reads slot (want ^ (r & SLM)).
template<int ROWS,int BK,int THREADS>
DEV void stage_lds_issue(const unsigned short* __restrict__ src, int row0, int ld,
                         int kk, char* lds, int tid){
  constexpr int SLOTS = BK/8, SLM = SLOTS-1, RPC = 64/SLOTS;
  constexpr int NCH = ROWS*BK*2/1024;
  constexpr int NW = THREADS/64, NI = NCH/NW;
  static_assert(NI*NW==NCH, "chunk exact");
  const int lane = tid & 63, wid = tid >> 6;
  #pragma unroll
  for (int i=0;i<NI;i++){
    int c = i*NW + wid;
    int r = c*RPC + lane/SLOTS;
    int s = lane & SLM;
    int ks = s ^ (r & SLM);
    gld16(src + (size_t)(row0+r)*ld + kk + ks*8, lds + c*1024);
  }
}

// f32 operand: T14 async-split. Issue loads early, cvt(+relu)+ds_write late.
template<int ROWS,int BK,int THREADS,int NR>
DEV void stage_f32_load(const float* __restrict__ src, int row0, int ld, int kk,
                        float4* regs, int tid){
  #pragma unroll
  for (int i=0;i<NR;i++){
    int u = tid + i*THREADS;
    int r = u/(BK/4), c = u%(BK/4);
    regs[i] = *(const float4*)(src + (size_t)(row0+r)*ld + kk + c*4);
  }
}
template<int ROWS,int BK,int THREADS,int NR,bool RELU>
DEV void stage_f32_write(const float4* regs, char* lds, int tid){
  constexpr int SLM = BK/8 - 1;
  #pragma unroll
  for (int i=0;i<NR;i++){
    int u = tid + i*THREADS;
    int r = u/(BK/4), c = u%(BK/4);
    float x0=regs[i].x, x1=regs[i].y, x2=regs[i].z, x3=regs[i].w;
    if constexpr (RELU){ x0=fmaxf(x0,0.f); x1=fmaxf(x1,0.f); x2=fmaxf(x2,0.f); x3=fmaxf(x3,0.f); }
    int2 p; p.x = (int)pack2(x0,x1); p.y = (int)pack2(x2,x3);
    int s = (c>>1) ^ (r & SLM);
    *(int2*)(lds + r*(BK*2) + s*16 + (c&1)*8) = p;
  }
}

// ---------------- GEMM: C[M,N] = A[M,K] @ Bt[N,K]^T ----------------
// T3 minimum 2-phase: STAGE(next) -> compute(cur) -> [f32 late-write] -> barrier
template<int BM,int BN,int BK,int WR,int WC,bool AF32,bool BF32,bool ATOMIC,bool BRELU=false>
__global__ __launch_bounds__(WR*WC*64, 4)
void k_gemm_lds(const void* __restrict__ Ap, const void* __restrict__ Bp,
                void* __restrict__ Cp, int lda, int ldb, int ldc, int kchunk)
{
  constexpr int THREADS = WR*WC*64;
  constexpr int ROWB = BK*2, SLM = BK/8 - 1;
  constexpr int ABYTES = BM*ROWB, BBYTES = BN*ROWB;
  constexpr int WM = BM/WR, WN = BN/WC;
  constexpr int FM = WM/16, FN = WN/16, KS = BK/32;
  constexpr int NRA = AF32 ? BM*BK/(THREADS*4) : 1;
  constexpr int NRB = BF32 ? BN*BK/(THREADS*4) : 1;

  __shared__ char smem[2*(ABYTES+BBYTES)];
  char* A0 = smem; char* B0 = A0 + ABYTES;
  char* A1 = B0 + BBYTES; char* B1 = A1 + ABYTES;

  const int tid = threadIdx.x, lane = tid & 63;
  const int wid = tid >> 6, wrr = wid / WC, wcc = wid % WC;
  const int m0 = blockIdx.y * BM, n0 = blockIdx.x * BN;
  const int kbeg = blockIdx.z * kchunk, nk = kchunk / BK;

  const float* Af = (const float*)Ap;
  const unsigned short* Ah = (const unsigned short*)Ap;
  const float* Bf = (const float*)Bp;
  const unsigned short* Bh = (const unsigned short*)Bp;

  float4 areg[NRA], breg[NRB];

  f32x4 acc[FM][FN];
  f32x4 z4 = {0.f,0.f,0.f,0.f};
  #pragma unroll
  for (int m=0;m<FM;m++)
    #pragma unroll
    for (int n=0;n<FN;n++) acc[m][n] = z4;

  auto issue = [&](int kk, char* bA, char* bB){
    if constexpr (AF32) stage_f32_load<BM,BK,THREADS,NRA>(Af, m0, lda, kk, areg, tid);
    else                stage_lds_issue<BM,BK,THREADS>(Ah, m0, lda, kk, bA, tid);
    if constexpr (BF32) stage_f32_load<BN,BK,THREADS,NRB>(Bf, n0, ldb, kk, breg, tid);
    else                stage_lds_issue<BN,BK,THREADS>(Bh, n0, ldb, kk, bB, tid);
  };
  auto late_write = [&](char* bA, char* bB){
    if constexpr (AF32) stage_f32_write<BM,BK,THREADS,NRA,false>(areg, bA, tid);
    if constexpr (BF32) stage_f32_write<BN,BK,THREADS,NRB,BRELU>(breg, bB, tid);
  };
  auto compute = [&](const char* bA, const char* bB){
    #pragma unroll
    for (int ks=0;ks<KS;ks++){
      s16x8 av[FM], bv[FN];
      #pragma unroll
      for (int m=0;m<FM;m++){
        int r = wrr*WM + m*16 + (lane&15);
        int s = (ks*4 + (lane>>4)) ^ (r & SLM);
        av[m] = *(const s16x8*)(bA + r*ROWB + s*16);
      }
      #pragma unroll
      for (int n=0;n<FN;n++){
        int r = wcc*WN + n*16 + (lane&15);
        int s = (ks*4 + (lane>>4)) ^ (r & SLM);
        bv[n] = *(const s16x8*)(bB + r*ROWB + s*16);
      }
      #pragma unroll
      for (int m=0;m<FM;m++)
        #pragma unroll
        for (int n=0;n<FN;n++)
          acc[m][n] = __builtin_amdgcn_mfma_f32_16x16x32_bf16(av[m], bv[n], acc[m][n], 0, 0, 0);
    }
  };

  issue(kbeg, A0, B0);
  late_write(A0, B0);
  __syncthreads();

  for (int t=0;t<nk;t++){
    char* cA = (t&1)?A1:A0; char* cB = (t&1)?B1:B0;
    char* nA = (t&1)?A0:A1; char* nB = (t&1)?B0:B1;
    bool pf = (t+1 < nk);
    if (pf) issue(kbeg + (t+1)*BK, nA, nB);
    compute(cA, cB);
    if (pf) late_write(nA, nB);
    __syncthreads();
  }

  // epilogue: C/D layout (verified m89): col=lane&15, row=(lane>>4)*4+reg
  if constexpr (ATOMIC) {
    float* Cf = (float*)Cp;
    #pragma unroll
    for (int m=0;m<FM;m++)
      #pragma unroll
      for (int n=0;n<FN;n++)
        #pragma unroll
        for (int r=0;r<4;r++){
          int row = m0 + wrr*WM + m*16 + (lane>>4)*4 + r;
          int col = n0 + wcc*WN + n*16 + (lane&15);
          atomicAdd(Cf + (size_t)row*ldc + col, acc[m][n][r]);
        }
  } else {
    unsigned short* Ch = (unsigned short*)Cp;
    #pragma unroll
    for (int m=0;m<FM;m++)
      #pragma unroll
      for (int n=0;n<FN;n++)
        #pragma unroll
        for (int r=0;r<4;r++){
          int row = m0 + wrr*WM + m*16 + (lane>>4)*4 + r;
          int col = n0 + wcc*WN + n*16 + (lane&15);
          Ch[(size_t)row*ldc + col] = f2bf(acc[m][n][r]);
        }
  }
}

// ---------------- emb finalize: f32 out, bf16 copy, row sq-sums ----------------
__global__ void k_emb_fin(const float* __restrict__ acc, float* __restrict__ emb_out,
                          unsigned short* __restrict__ embb, float* __restrict__ sq){
  int idx = blockIdx.x*256 + threadIdx.x;
  float v = acc[idx];
  emb_out[idx] = v;
  unsigned short ub = f2bf(v);
  embb[idx] = ub;
  float x = bf2f(ub);
  float s = x*x;
  #pragma unroll
  for (int off=32; off>0; off>>=1) s += __shfl_xor(s, off, 64);
  if ((threadIdx.x & 63)==0) sq[idx>>6] = s;
}

// ---------------- distance softmax (G = emb@emb^T tiles via MFMA) ----------------
template<int PASS>
__global__ __launch_bounds__(256)
void k_dist(const unsigned short* __restrict__ embb, const float* __restrict__ sq,
            float* __restrict__ S, float* __restrict__ out)
{
  constexpr int ROWB = 128, SLM = 7;
  __shared__ char smem[2*128*128];
  char* bufA = smem;
  char* bufB = smem + 128*ROWB;
  const int tid=threadIdx.x, lane=tid&63, wid=tid>>6;
  const int wrr = wid>>1, wcc = wid&1;
  const int i0 = blockIdx.y*128, j0 = blockIdx.x*128;

  #pragma unroll
  for (int i=0;i<4;i++){
    int u = tid + i*256;
    int r = u>>3, c = u&7;
    int byte = r*ROWB + ((c^(r&SLM))*16);
    *(int4*)(bufA+byte) = *(const int4*)(embb + (size_t)(i0+r)*64 + c*8);
    *(int4*)(bufB+byte) = *(const int4*)(embb + (size_t)(j0+r)*64 + c*8);
  }
  __syncthreads();

  f32x4 acc[4][4];
  f32x4 z4 = {0.f,0.f,0.f,0.f};
  #pragma unroll
  for (int m=0;m<4;m++)
    #pragma unroll
    for (int n=0;n<4;n++) acc[m][n]=z4;

  #pragma unroll
  for (int ks=0;ks<2;ks++){
    s16x8 av[4], bv[4];
    #pragma unroll
    for (int m=0;m<4;m++){
      int r = wrr*64 + m*16 + (lane&15);
      int slot = (ks*4 + (lane>>4)) ^ (r&SLM);
      av[m] = *(const s16x8*)(bufA + r*ROWB + slot*16);
    }
    #pragma unroll
    for (int n=0;n<4;n++){
      int r = wcc*64 + n*16 + (lane&15);
      int slot = (ks*4 + (lane>>4)) ^ (r&SLM);
      bv[n] = *(const s16x8*)(bufB + r*ROWB + slot*16);
    }
    #pragma unroll
    for (int m=0;m<4;m++)
      #pragma unroll
      for (int n=0;n<4;n++)
        acc[m][n] = __builtin_amdgcn_mfma_f32_16x16x32_bf16(av[m], bv[n], acc[m][n], 0, 0, 0);
  }

  float sqj[4];
  #pragma unroll
  for (int n=0;n<4;n++) sqj[n] = sq[j0 + wcc*64 + n*16 + (lane&15)];

  #pragma unroll
  for (int m=0;m<4;m++){
    #pragma unroll
    for (int r=0;r<4;r++){
      int row = i0 + wrr*64 + m*16 + (lane>>4)*4 + r;
      float sqi = sq[row];
      if constexpr (PASS==1){
        float v = 0.f;
        #pragma unroll
        for (int n=0;n<4;n++){
          float d = fmaxf(sqi + sqj[n] - 2.f*acc[m][n][r], 0.f);
          v += __expf(-d);
        }
        #pragma unroll
        for (int off=1; off<16; off<<=1) v += __shfl_xor(v, off, 64);
        if ((lane&15)==0) atomicAdd(S+row, v);
      } else {
        float inv = 1.0f / S[row];
        #pragma unroll
        for (int n=0;n<4;n++){
          int col = j0 + wcc*64 + n*16 + (lane&15);
          float d = fmaxf(sqi + sqj[n] - 2.f*acc[m][n][r], 0.f);
          out[(size_t)row*8192 + col] = __expf(-d)*inv + 1e-10f;
        }
      }
    }
  }
}

// ---------------- host launch ----------------
extern "C" void kernel_launch(void* const* d_in, const int* in_sizes, int n_in,
                              void* d_out, int out_size, void* d_ws, size_t ws_size,
                              hipStream_t stream)
{
  const float* xi = (const float*)d_in[0];   // [8192,512]
  const float* F  = (const float*)d_in[1];   // [8192,8192]
  const float* w1 = (const float*)d_in[2];   // [512,256]
  const float* w2 = (const float*)d_in[3];   // [256,64]
  float* out = (float*)d_out;
  float* emb_out = out;                      // 8192*64
  float* recons  = out + (size_t)8192*64;    // 8192*8192

  char* ws = (char*)d_ws;
  size_t off = 0;
  auto alloc = [&](size_t bytes)->char*{ char* p = ws + off; off += (bytes + 255) & ~(size_t)255; return p; };
  unsigned short* w1t  = (unsigned short*)alloc((size_t)256*512*2);
  unsigned short* w2t  = (unsigned short*)alloc((size_t)64*256*2);
  unsigned short* t1t  = (unsigned short*)alloc((size_t)256*8192*2);
  unsigned short* t2t  = (unsigned short*)alloc((size_t)64*8192*2);
  unsigned short* embb = (unsigned short*)alloc((size_t)8192*64*2);
  float* sq    = (float*)alloc((size_t)8192*4);
  char* zbase = ws + off;
  float* h_acc   = (float*)alloc((size_t)8192*256*4);
  float* emb_acc = (float*)alloc((size_t)8192*64*4);
  float* S       = (float*)alloc((size_t)8192*4);
  size_t zbytes = (size_t)((ws + off) - zbase);

  hipMemsetAsync(zbase, 0, zbytes, stream);

  k_transpose_bf16<<<dim3((512*256+255)/256), 256, 0, stream>>>(w1, w1t, 512, 256);
  k_transpose_bf16<<<dim3((256*64+255)/256),  256, 0, stream>>>(w2, w2t, 256, 64);

  // G1: t1t[256,8192] = w1t[256,512] @ xi^T   (B = xi f32 in-flight; 256 blocks)
  k_gemm_lds<128,64,32,2,2,false,true,false><<<dim3(128,2,1),256,0,stream>>>(
      w1t, xi, t1t, 512, 512, 8192, 512);

  // G2: h_acc[8192,256] += F @ t1t^T   (A = F f32; split-K=8 -> 1024 blocks, 4/CU)
  k_gemm_lds<128,128,32,2,2,true,false,true><<<dim3(2,64,8),256,0,stream>>>(
      F, t1t, h_acc, 8192, 8192, 256, 1024);

  // G3: t2t[64,8192] = w2t[64,256] @ relu(h_acc)^T  (relu fused into staging)
  k_gemm_lds<64,64,32,2,2,false,true,false,true><<<dim3(128,1,1),256,0,stream>>>(
      w2t, h_acc, t2t, 256, 256, 8192, 256);

  // G4: emb_acc[8192,64] += F @ t2t^T   (split-K=16 -> 1024 blocks, 4/CU)
  k_gemm_lds<128,64,32,2,2,true,false,true><<<dim3(1,64,16),256,0,stream>>>(
      F, t2t, emb_acc, 8192, 8192, 64, 512);

  k_emb_fin<<<dim3(8192*64/256),256,0,stream>>>(emb_acc, emb_out, embb, sq);

  k_dist<1><<<dim3(64,64),256,0,stream>>>(embb, sq, S, recons);
  k_dist<2><<<dim3(64,64),256,0,stream>>>(embb, sq, S, recons);
}

// Round 4
// 360.538 us; speedup vs baseline: 1.3377x; 1.3377x over previous
//
#include <hip/hip_runtime.h>

typedef short s16x8 __attribute__((ext_vector_type(8)));
typedef float f32x4 __attribute__((ext_vector_type(4)));
typedef unsigned int u32;

#define DEV static __device__ __forceinline__

DEV unsigned short f2bf(float x){
  u32 u = __builtin_bit_cast(u32, x);
  return (unsigned short)((u + 0x7FFFu + ((u >> 16) & 1u)) >> 16);
}
DEV float bf2f(unsigned short h){ u32 u = ((u32)h) << 16; return __builtin_bit_cast(float, u); }
DEV u32 pack2(float a, float b){ return (u32)f2bf(a) | ((u32)f2bf(b) << 16); }

DEV void gld16(const void* g, void* l){
  __builtin_amdgcn_global_load_lds((const __attribute__((address_space(1))) u32*)g,
                                   (__attribute__((address_space(3))) u32*)l, 16, 0, 0);
}

// ---------------- f32 -> bf16 streaming convert ----------------
__global__ void k_cvt(const float* __restrict__ src, unsigned short* __restrict__ dst, long n4){
  long i = (long)blockIdx.x*256 + threadIdx.x;
  long stride = (long)gridDim.x*256;
  for (; i < n4; i += stride){
    float4 v = ((const float4*)src)[i];
    int2 p; p.x = (int)pack2(v.x, v.y); p.y = (int)pack2(v.z, v.w);
    ((int2*)dst)[i] = p;
  }
}

// ---------------- transpose f32 -> bf16 (tiny matrices) ----------------
__global__ void k_transpose_bf16(const float* __restrict__ src,
                                 unsigned short* __restrict__ dst, int R, int C){
  int idx = blockIdx.x * 256 + threadIdx.x;
  if (idx >= R * C) return;
  int r = idx / C, c = idx % C;
  dst[(size_t)c * R + r] = f2bf(src[idx]);
}

// ---------------- relu(h_acc f32) -> h bf16 ----------------
__global__ void k_relu_bf16(const float* __restrict__ src, unsigned short* __restrict__ dst, int n4){
  int idx = blockIdx.x*256 + threadIdx.x;
  if (idx >= n4) return;
  float4 v = ((const float4*)src)[idx];
  int2 p;
  p.x = (int)pack2(fmaxf(v.x,0.f), fmaxf(v.y,0.f));
  p.y = (int)pack2(fmaxf(v.z,0.f), fmaxf(v.w,0.f));
  ((int2*)dst)[idx] = p;
}

// ------- bf16 staging: global_load_lds 16B, swizzle on GLOBAL src (rule 21) -------
// LDS slot s of row r holds source k-chunk s ^ (r & SLM).
template<int ROWS,int BK,int THREADS>
DEV void stage_lds(const unsigned short* __restrict__ src, int row0, int ld,
                   int kk, char* lds, int tid){
  constexpr int SLOTS = BK/8, SLM = SLOTS-1, RPC = 64/SLOTS;
  constexpr int NCH = ROWS*BK*2/1024;
  constexpr int NW = THREADS/64, NI = NCH/NW;
  static_assert(NI*NW==NCH, "chunk exact");
  const int lane = tid & 63, wid = tid >> 6;
  #pragma unroll
  for (int i=0;i<NI;i++){
    int c = i*NW + wid;
    int r = c*RPC + lane/SLOTS;
    int s = lane & SLM;
    int ks = s ^ (r & SLM);
    gld16(src + (size_t)(row0+r)*ld + kk + ks*8, lds + c*1024);
  }
}

// ---------------- GEMM (pure bf16): C[M,N] = A[M,K] @ Bt[N,K]^T ----------------
// 2-phase: issue(t+1 via global_load_lds) -> compute(t) -> barrier (drains vmcnt)
template<int BM,int BN,int BK,int WR,int WC,bool ATOMIC>
__global__ __launch_bounds__(WR*WC*64)
void k_gemm(const unsigned short* __restrict__ A, const unsigned short* __restrict__ B,
            void* __restrict__ Cp, int lda, int ldb, int ldc, int kchunk)
{
  constexpr int THREADS = WR*WC*64;
  constexpr int ROWB = BK*2, SLM = BK/8 - 1;
  constexpr int ABYTES = BM*ROWB, BBYTES = BN*ROWB;
  constexpr int WM = BM/WR, WN = BN/WC;
  constexpr int FM = WM/16, FN = WN/16, KS = BK/32;

  __shared__ char smem[2*(ABYTES+BBYTES)];
  char* A0 = smem; char* B0 = A0 + ABYTES;
  char* A1 = B0 + BBYTES; char* B1 = A1 + ABYTES;

  const int tid = threadIdx.x, lane = tid & 63;
  const int wid = tid >> 6, wrr = wid / WC, wcc = wid % WC;
  const int m0 = blockIdx.y * BM, n0 = blockIdx.x * BN;
  const int kbeg = blockIdx.z * kchunk, nk = kchunk / BK;

  f32x4 acc[FM][FN];
  f32x4 z4 = {0.f,0.f,0.f,0.f};
  #pragma unroll
  for (int m=0;m<FM;m++)
    #pragma unroll
    for (int n=0;n<FN;n++) acc[m][n] = z4;

  auto issue = [&](int kk, char* bA, char* bB){
    stage_lds<BM,BK,THREADS>(A, m0, lda, kk, bA, tid);
    stage_lds<BN,BK,THREADS>(B, n0, ldb, kk, bB, tid);
  };
  auto compute = [&](const char* bA, const char* bB){
    #pragma unroll
    for (int ks=0;ks<KS;ks++){
      s16x8 av[FM], bv[FN];
      #pragma unroll
      for (int m=0;m<FM;m++){
        int r = wrr*WM + m*16 + (lane&15);
        int s = (ks*4 + (lane>>4)) ^ (r & SLM);
        av[m] = *(const s16x8*)(bA + r*ROWB + s*16);
      }
      #pragma unroll
      for (int n=0;n<FN;n++){
        int r = wcc*WN + n*16 + (lane&15);
        int s = (ks*4 + (lane>>4)) ^ (r & SLM);
        bv[n] = *(const s16x8*)(bB + r*ROWB + s*16);
      }
      #pragma unroll
      for (int m=0;m<FM;m++)
        #pragma unroll
        for (int n=0;n<FN;n++)
          acc[m][n] = __builtin_amdgcn_mfma_f32_16x16x32_bf16(av[m], bv[n], acc[m][n], 0, 0, 0);
    }
  };

  issue(kbeg, A0, B0);
  __syncthreads();

  for (int t=0;t<nk;t++){
    char* cA = (t&1)?A1:A0; char* cB = (t&1)?B1:B0;
    char* nA = (t&1)?A0:A1; char* nB = (t&1)?B0:B1;
    if (t+1 < nk) issue(kbeg + (t+1)*BK, nA, nB);
    compute(cA, cB);
    __syncthreads();
  }

  // epilogue: C/D layout (verified m89): col=lane&15, row=(lane>>4)*4+reg
  if constexpr (ATOMIC) {
    float* Cf = (float*)Cp;
    #pragma unroll
    for (int m=0;m<FM;m++)
      #pragma unroll
      for (int n=0;n<FN;n++)
        #pragma unroll
        for (int r=0;r<4;r++){
          int row = m0 + wrr*WM + m*16 + (lane>>4)*4 + r;
          int col = n0 + wcc*WN + n*16 + (lane&15);
          atomicAdd(Cf + (size_t)row*ldc + col, acc[m][n][r]);
        }
  } else {
    unsigned short* Ch = (unsigned short*)Cp;
    #pragma unroll
    for (int m=0;m<FM;m++)
      #pragma unroll
      for (int n=0;n<FN;n++)
        #pragma unroll
        for (int r=0;r<4;r++){
          int row = m0 + wrr*WM + m*16 + (lane>>4)*4 + r;
          int col = n0 + wcc*WN + n*16 + (lane&15);
          Ch[(size_t)row*ldc + col] = f2bf(acc[m][n][r]);
        }
  }
}

// ---------------- emb finalize: f32 out, bf16 copy, row sq-sums ----------------
__global__ void k_emb_fin(const float* __restrict__ acc, float* __restrict__ emb_out,
                          unsigned short* __restrict__ embb, float* __restrict__ sq){
  int idx = blockIdx.x*256 + threadIdx.x;
  float v = acc[idx];
  emb_out[idx] = v;
  unsigned short ub = f2bf(v);
  embb[idx] = ub;
  float x = bf2f(ub);
  float s = x*x;
  #pragma unroll
  for (int off=32; off>0; off>>=1) s += __shfl_xor(s, off, 64);
  if ((threadIdx.x & 63)==0) sq[idx>>6] = s;
}

// ---------------- distance softmax (G = emb@emb^T tiles via MFMA) ----------------
template<int PASS>
__global__ __launch_bounds__(256)
void k_dist(const unsigned short* __restrict__ embb, const float* __restrict__ sq,
            float* __restrict__ S, float* __restrict__ out)
{
  constexpr int ROWB = 128, SLM = 7;
  __shared__ char smem[2*128*128];
  char* bufA = smem;
  char* bufB = smem + 128*ROWB;
  const int tid=threadIdx.x, lane=tid&63, wid=tid>>6;
  const int wrr = wid>>1, wcc = wid&1;
  const int i0 = blockIdx.y*128, j0 = blockIdx.x*128;

  #pragma unroll
  for (int i=0;i<4;i++){
    int u = tid + i*256;
    int r = u>>3, c = u&7;
    int byte = r*ROWB + ((c^(r&SLM))*16);
    *(int4*)(bufA+byte) = *(const int4*)(embb + (size_t)(i0+r)*64 + c*8);
    *(int4*)(bufB+byte) = *(const int4*)(embb + (size_t)(j0+r)*64 + c*8);
  }
  __syncthreads();

  f32x4 acc[4][4];
  f32x4 z4 = {0.f,0.f,0.f,0.f};
  #pragma unroll
  for (int m=0;m<4;m++)
    #pragma unroll
    for (int n=0;n<4;n++) acc[m][n]=z4;

  #pragma unroll
  for (int ks=0;ks<2;ks++){
    s16x8 av[4], bv[4];
    #pragma unroll
    for (int m=0;m<4;m++){
      int r = wrr*64 + m*16 + (lane&15);
      int slot = (ks*4 + (lane>>4)) ^ (r&SLM);
      av[m] = *(const s16x8*)(bufA + r*ROWB + slot*16);
    }
    #pragma unroll
    for (int n=0;n<4;n++){
      int r = wcc*64 + n*16 + (lane&15);
      int slot = (ks*4 + (lane>>4)) ^ (r&SLM);
      bv[n] = *(const s16x8*)(bufB + r*ROWB + slot*16);
    }
    #pragma unroll
    for (int m=0;m<4;m++)
      #pragma unroll
      for (int n=0;n<4;n++)
        acc[m][n] = __builtin_amdgcn_mfma_f32_16x16x32_bf16(av[m], bv[n], acc[m][n], 0, 0, 0);
  }

  float sqj[4];
  #pragma unroll
  for (int n=0;n<4;n++) sqj[n] = sq[j0 + wcc*64 + n*16 + (lane&15)];

  #pragma unroll
  for (int m=0;m<4;m++){
    #pragma unroll
    for (int r=0;r<4;r++){
      int row = i0 + wrr*64 + m*16 + (lane>>4)*4 + r;
      float sqi = sq[row];
      if constexpr (PASS==1){
        float v = 0.f;
        #pragma unroll
        for (int n=0;n<4;n++){
          float d = fmaxf(sqi + sqj[n] - 2.f*acc[m][n][r], 0.f);
          v += __expf(-d);
        }
        #pragma unroll
        for (int off=1; off<16; off<<=1) v += __shfl_xor(v, off, 64);
        if ((lane&15)==0) atomicAdd(S+row, v);
      } else {
        float inv = 1.0f / S[row];
        #pragma unroll
        for (int n=0;n<4;n++){
          int col = j0 + wcc*64 + n*16 + (lane&15);
          float d = fmaxf(sqi + sqj[n] - 2.f*acc[m][n][r], 0.f);
          out[(size_t)row*8192 + col] = __expf(-d)*inv + 1e-10f;
        }
      }
    }
  }
}

// ---------------- host launch ----------------
extern "C" void kernel_launch(void* const* d_in, const int* in_sizes, int n_in,
                              void* d_out, int out_size, void* d_ws, size_t ws_size,
                              hipStream_t stream)
{
  const float* xi = (const float*)d_in[0];   // [8192,512]
  const float* F  = (const float*)d_in[1];   // [8192,8192]
  const float* w1 = (const float*)d_in[2];   // [512,256]
  const float* w2 = (const float*)d_in[3];   // [256,64]
  float* out = (float*)d_out;
  float* emb_out = out;                      // 8192*64
  float* recons  = out + (size_t)8192*64;    // 8192*8192

  // F-bf16 lives in the recons region of d_out (scratch until k_dist<2>
  // overwrites every element of it at the end).
  unsigned short* Fb = (unsigned short*)recons;   // 134 MB of the 268 MB region

  char* ws = (char*)d_ws;
  size_t off = 0;
  auto alloc = [&](size_t bytes)->char*{ char* p = ws + off; off += (bytes + 255) & ~(size_t)255; return p; };
  unsigned short* w1t  = (unsigned short*)alloc((size_t)256*512*2);
  unsigned short* w2t  = (unsigned short*)alloc((size_t)64*256*2);
  unsigned short* xib  = (unsigned short*)alloc((size_t)8192*512*2);
  unsigned short* t1t  = (unsigned short*)alloc((size_t)256*8192*2);
  unsigned short* t2t  = (unsigned short*)alloc((size_t)64*8192*2);
  unsigned short* h    = (unsigned short*)alloc((size_t)8192*256*2);
  unsigned short* embb = (unsigned short*)alloc((size_t)8192*64*2);
  float* sq    = (float*)alloc((size_t)8192*4);
  char* zbase = ws + off;
  float* h_acc   = (float*)alloc((size_t)8192*256*4);
  float* emb_acc = (float*)alloc((size_t)8192*64*4);
  float* S       = (float*)alloc((size_t)8192*4);
  size_t zbytes = (size_t)((ws + off) - zbase);

  hipMemsetAsync(zbase, 0, zbytes, stream);

  // conversions
  k_cvt<<<dim3(2048),256,0,stream>>>(F,  Fb,  (long)8192*8192/4);
  k_cvt<<<dim3(2048),256,0,stream>>>(xi, xib, (long)8192*512/4);
  k_transpose_bf16<<<dim3((512*256+255)/256), 256, 0, stream>>>(w1, w1t, 512, 256);
  k_transpose_bf16<<<dim3((256*64+255)/256),  256, 0, stream>>>(w2, w2t, 256, 64);

  // G1: t1t[256,8192] = w1t[256,512] @ xib[8192,512]^T   (256 blocks)
  k_gemm<128,64,64,2,2,false><<<dim3(128,2,1),256,0,stream>>>(
      w1t, xib, t1t, 512, 512, 8192, 512);

  // G2: h_acc[8192,256] += Fb @ t1t^T  (BN=256 -> F read once; split-K=8, 512 blocks)
  k_gemm<128,256,32,2,4,true><<<dim3(1,64,8),512,0,stream>>>(
      Fb, t1t, h_acc, 8192, 8192, 256, 1024);

  k_relu_bf16<<<dim3(8192*256/4/256),256,0,stream>>>(h_acc, h, 8192*256/4);

  // G3: t2t[64,8192] = w2t[64,256] @ h[8192,256]^T   (128 blocks)
  k_gemm<64,64,64,2,2,false><<<dim3(128,1,1),256,0,stream>>>(
      w2t, h, t2t, 256, 256, 8192, 256);

  // G4: emb_acc[8192,64] += Fb @ t2t^T   (split-K=8, 512 blocks, BK=64)
  k_gemm<128,64,64,2,2,true><<<dim3(1,64,8),256,0,stream>>>(
      Fb, t2t, emb_acc, 8192, 8192, 64, 1024);

  k_emb_fin<<<dim3(8192*64/256),256,0,stream>>>(emb_acc, emb_out, embb, sq);

  k_dist<1><<<dim3(64,64),256,0,stream>>>(embb, sq, S, recons);
  k_dist<2><<<dim3(64,64),256,0,stream>>>(embb, sq, S, recons);
}

// Round 5
// 351.216 us; speedup vs baseline: 1.3732x; 1.0265x over previous
//
#include <hip/hip_runtime.h>

typedef short s16x8 __attribute__((ext_vector_type(8)));
typedef float f32x4 __attribute__((ext_vector_type(4)));
typedef unsigned int u32;

#define DEV static __device__ __forceinline__

DEV unsigned short f2bf(float x){
  u32 u = __builtin_bit_cast(u32, x);
  return (unsigned short)((u + 0x7FFFu + ((u >> 16) & 1u)) >> 16);
}
DEV float bf2f(unsigned short h){ u32 u = ((u32)h) << 16; return __builtin_bit_cast(float, u); }
DEV u32 pack2(float a, float b){ return (u32)f2bf(a) | ((u32)f2bf(b) << 16); }

DEV void gld16(const void* g, void* l){
  __builtin_amdgcn_global_load_lds((const __attribute__((address_space(1))) u32*)g,
                                   (__attribute__((address_space(3))) u32*)l, 16, 0, 0);
}

// counted vmcnt wait (T4): wait until at most N of this wave's VMEM ops remain
template<int N> DEV void vmwait(){
  static_assert(N>=0 && N<=8, "vmcnt range");
  if constexpr (N==0) asm volatile("s_waitcnt vmcnt(0)" ::: "memory");
  else if constexpr (N==1) asm volatile("s_waitcnt vmcnt(1)" ::: "memory");
  else if constexpr (N==2) asm volatile("s_waitcnt vmcnt(2)" ::: "memory");
  else if constexpr (N==3) asm volatile("s_waitcnt vmcnt(3)" ::: "memory");
  else if constexpr (N==4) asm volatile("s_waitcnt vmcnt(4)" ::: "memory");
  else if constexpr (N==5) asm volatile("s_waitcnt vmcnt(5)" ::: "memory");
  else if constexpr (N==6) asm volatile("s_waitcnt vmcnt(6)" ::: "memory");
  else if constexpr (N==7) asm volatile("s_waitcnt vmcnt(7)" ::: "memory");
  else                     asm volatile("s_waitcnt vmcnt(8)" ::: "memory");
}
// raw barrier without the __syncthreads vmcnt(0) drain
DEV void pipebar(){
  __builtin_amdgcn_sched_barrier(0);
  __builtin_amdgcn_s_barrier();
  __builtin_amdgcn_sched_barrier(0);
}

// ---------------- f32 -> bf16 streaming convert ----------------
__global__ void k_cvt(const float* __restrict__ src, unsigned short* __restrict__ dst, long n4){
  long i = (long)blockIdx.x*256 + threadIdx.x;
  long stride = (long)gridDim.x*256;
  for (; i < n4; i += stride){
    float4 v = ((const float4*)src)[i];
    int2 p; p.x = (int)pack2(v.x, v.y); p.y = (int)pack2(v.z, v.w);
    ((int2*)dst)[i] = p;
  }
}

// ---------------- transpose f32 -> bf16 (tiny matrices) ----------------
__global__ void k_transpose_bf16(const float* __restrict__ src,
                                 unsigned short* __restrict__ dst, int R, int C){
  int idx = blockIdx.x * 256 + threadIdx.x;
  if (idx >= R * C) return;
  int r = idx / C, c = idx % C;
  dst[(size_t)c * R + r] = f2bf(src[idx]);
}

// ---------------- relu(h_acc f32) -> h bf16 ----------------
__global__ void k_relu_bf16(const float* __restrict__ src, unsigned short* __restrict__ dst, int n4){
  int idx = blockIdx.x*256 + threadIdx.x;
  if (idx >= n4) return;
  float4 v = ((const float4*)src)[idx];
  int2 p;
  p.x = (int)pack2(fmaxf(v.x,0.f), fmaxf(v.y,0.f));
  p.y = (int)pack2(fmaxf(v.z,0.f), fmaxf(v.w,0.f));
  ((int2*)dst)[idx] = p;
}

// ------- bf16 staging: global_load_lds 16B, swizzle on GLOBAL src (rule 21) -------
// LDS slot s of row r holds source k-chunk s ^ (r & SLM).
template<int ROWS,int BK,int THREADS>
DEV void stage_lds(const unsigned short* __restrict__ src, int row0, int ld,
                   int kk, char* lds, int tid){
  constexpr int SLOTS = BK/8, SLM = SLOTS-1, RPC = 64/SLOTS;
  constexpr int NCH = ROWS*BK*2/1024;
  constexpr int NW = THREADS/64, NI = NCH/NW;
  static_assert(NI*NW==NCH, "chunk exact");
  const int lane = tid & 63, wid = tid >> 6;
  #pragma unroll
  for (int i=0;i<NI;i++){
    int c = i*NW + wid;
    int r = c*RPC + lane/SLOTS;
    int s = lane & SLM;
    int ks = s ^ (r & SLM);
    gld16(src + (size_t)(row0+r)*ld + kk + ks*8, lds + c*1024);
  }
}

// ---------------- GEMM (pure bf16): C[M,N] = A[M,K] @ Bt[N,K]^T ----------------
// T3+T4 pipeline: 3 LDS buffers, 2 tiles in flight, counted vmcnt, raw barriers.
template<int BM,int BN,int BK,int WR,int WC,bool ATOMIC>
__global__ __launch_bounds__(WR*WC*64)
void k_gemm(const unsigned short* __restrict__ A, const unsigned short* __restrict__ B,
            void* __restrict__ Cp, int lda, int ldb, int ldc, int kchunk)
{
  constexpr int THREADS = WR*WC*64;
  constexpr int ROWB = BK*2, SLM = BK/8 - 1;
  constexpr int TBYTES = (BM+BN)*ROWB;          // one pipeline buffer (A then B)
  constexpr int WM = BM/WR, WN = BN/WC;
  constexpr int FM = WM/16, FN = WN/16, KS = BK/32;
  constexpr int LA = BM*BK*2/1024/(THREADS/64); // gld16 per thread for A-tile
  constexpr int LB = BN*BK*2/1024/(THREADS/64);
  constexpr int L  = LA + LB;                   // VMEM ops per stage per wave

  __shared__ char smem[3*TBYTES];

  const int tid = threadIdx.x, lane = tid & 63;
  const int wid = tid >> 6, wrr = wid / WC, wcc = wid % WC;
  const int m0 = blockIdx.y * BM, n0 = blockIdx.x * BN;
  const int kbeg = blockIdx.z * kchunk, nk = kchunk / BK;

  f32x4 acc[FM][FN];
  f32x4 z4 = {0.f,0.f,0.f,0.f};
  #pragma unroll
  for (int m=0;m<FM;m++)
    #pragma unroll
    for (int n=0;n<FN;n++) acc[m][n] = z4;

  auto stage = [&](int kk, char* b){
    stage_lds<BM,BK,THREADS>(A, m0, lda, kk, b, tid);
    stage_lds<BN,BK,THREADS>(B, n0, ldb, kk, b + BM*ROWB, tid);
  };
  auto compute = [&](const char* b){
    const char* bA = b;
    const char* bB = b + BM*ROWB;
    #pragma unroll
    for (int ks=0;ks<KS;ks++){
      s16x8 av[FM], bv[FN];
      #pragma unroll
      for (int m=0;m<FM;m++){
        int r = wrr*WM + m*16 + (lane&15);
        int s = (ks*4 + (lane>>4)) ^ (r & SLM);
        av[m] = *(const s16x8*)(bA + r*ROWB + s*16);
      }
      #pragma unroll
      for (int n=0;n<FN;n++){
        int r = wcc*WN + n*16 + (lane&15);
        int s = (ks*4 + (lane>>4)) ^ (r & SLM);
        bv[n] = *(const s16x8*)(bB + r*ROWB + s*16);
      }
      #pragma unroll
      for (int m=0;m<FM;m++)
        #pragma unroll
        for (int n=0;n<FN;n++)
          acc[m][n] = __builtin_amdgcn_mfma_f32_16x16x32_bf16(av[m], bv[n], acc[m][n], 0, 0, 0);
    }
  };

  char* bc = smem;               // compute buffer (tile t)
  char* b1 = smem + TBYTES;      // tile t+1 (in flight)
  char* b2 = smem + 2*TBYTES;    // free / staging target (tile t+2)

  // prologue: 2 tiles in flight (nk >= 2 for all instantiations)
  stage(kbeg, bc);
  stage(kbeg + BK, b1);

  for (int t=0; t<nk; t++){
    if (t+1 < nk) vmwait<L>();   // tile t's loads done; t+1's stay in flight
    else          vmwait<0>();   // last tile: drain
    pipebar();                   // all waves see buffer t complete
    if (t+2 < nk) stage(kbeg + (t+2)*BK, b2);
    compute(bc);
    pipebar();                   // all waves done reading bc before it's re-staged
    char* tmp = bc; bc = b1; b1 = b2; b2 = tmp;
  }

  // epilogue: C/D layout (verified m89): col=lane&15, row=(lane>>4)*4+reg
  if constexpr (ATOMIC) {
    float* Cf = (float*)Cp;
    #pragma unroll
    for (int m=0;m<FM;m++)
      #pragma unroll
      for (int n=0;n<FN;n++)
        #pragma unroll
        for (int r=0;r<4;r++){
          int row = m0 + wrr*WM + m*16 + (lane>>4)*4 + r;
          int col = n0 + wcc*WN + n*16 + (lane&15);
          atomicAdd(Cf + (size_t)row*ldc + col, acc[m][n][r]);
        }
  } else {
    unsigned short* Ch = (unsigned short*)Cp;
    #pragma unroll
    for (int m=0;m<FM;m++)
      #pragma unroll
      for (int n=0;n<FN;n++)
        #pragma unroll
        for (int r=0;r<4;r++){
          int row = m0 + wrr*WM + m*16 + (lane>>4)*4 + r;
          int col = n0 + wcc*WN + n*16 + (lane&15);
          Ch[(size_t)row*ldc + col] = f2bf(acc[m][n][r]);
        }
  }
}

// ---------------- emb finalize: f32 out, bf16 copy, row sq-sums ----------------
__global__ void k_emb_fin(const float* __restrict__ acc, float* __restrict__ emb_out,
                          unsigned short* __restrict__ embb, float* __restrict__ sq){
  int idx = blockIdx.x*256 + threadIdx.x;
  float v = acc[idx];
  emb_out[idx] = v;
  unsigned short ub = f2bf(v);
  embb[idx] = ub;
  float x = bf2f(ub);
  float s = x*x;
  #pragma unroll
  for (int off=32; off>0; off>>=1) s += __shfl_xor(s, off, 64);
  if ((threadIdx.x & 63)==0) sq[idx>>6] = s;
}

// ---------------- distance softmax (G = emb@emb^T tiles via MFMA) ----------------
template<int PASS>
__global__ __launch_bounds__(256)
void k_dist(const unsigned short* __restrict__ embb, const float* __restrict__ sq,
            float* __restrict__ S, float* __restrict__ out)
{
  constexpr int ROWB = 128, SLM = 7;
  __shared__ char smem[2*128*128];
  char* bufA = smem;
  char* bufB = smem + 128*ROWB;
  const int tid=threadIdx.x, lane=tid&63, wid=tid>>6;
  const int wrr = wid>>1, wcc = wid&1;
  const int i0 = blockIdx.y*128, j0 = blockIdx.x*128;

  #pragma unroll
  for (int i=0;i<4;i++){
    int u = tid + i*256;
    int r = u>>3, c = u&7;
    int byte = r*ROWB + ((c^(r&SLM))*16);
    *(int4*)(bufA+byte) = *(const int4*)(embb + (size_t)(i0+r)*64 + c*8);
    *(int4*)(bufB+byte) = *(const int4*)(embb + (size_t)(j0+r)*64 + c*8);
  }
  __syncthreads();

  f32x4 acc[4][4];
  f32x4 z4 = {0.f,0.f,0.f,0.f};
  #pragma unroll
  for (int m=0;m<4;m++)
    #pragma unroll
    for (int n=0;n<4;n++) acc[m][n]=z4;

  #pragma unroll
  for (int ks=0;ks<2;ks++){
    s16x8 av[4], bv[4];
    #pragma unroll
    for (int m=0;m<4;m++){
      int r = wrr*64 + m*16 + (lane&15);
      int slot = (ks*4 + (lane>>4)) ^ (r&SLM);
      av[m] = *(const s16x8*)(bufA + r*ROWB + slot*16);
    }
    #pragma unroll
    for (int n=0;n<4;n++){
      int r = wcc*64 + n*16 + (lane&15);
      int slot = (ks*4 + (lane>>4)) ^ (r&SLM);
      bv[n] = *(const s16x8*)(bufB + r*ROWB + slot*16);
    }
    #pragma unroll
    for (int m=0;m<4;m++)
      #pragma unroll
      for (int n=0;n<4;n++)
        acc[m][n] = __builtin_amdgcn_mfma_f32_16x16x32_bf16(av[m], bv[n], acc[m][n], 0, 0, 0);
  }

  float sqj[4];
  #pragma unroll
  for (int n=0;n<4;n++) sqj[n] = sq[j0 + wcc*64 + n*16 + (lane&15)];

  #pragma unroll
  for (int m=0;m<4;m++){
    #pragma unroll
    for (int r=0;r<4;r++){
      int row = i0 + wrr*64 + m*16 + (lane>>4)*4 + r;
      float sqi = sq[row];
      if constexpr (PASS==1){
        float v = 0.f;
        #pragma unroll
        for (int n=0;n<4;n++){
          float d = fmaxf(sqi + sqj[n] - 2.f*acc[m][n][r], 0.f);
          v += __expf(-d);
        }
        #pragma unroll
        for (int off=1; off<16; off<<=1) v += __shfl_xor(v, off, 64);
        if ((lane&15)==0) atomicAdd(S+row, v);
      } else {
        float inv = 1.0f / S[row];
        #pragma unroll
        for (int n=0;n<4;n++){
          int col = j0 + wcc*64 + n*16 + (lane&15);
          float d = fmaxf(sqi + sqj[n] - 2.f*acc[m][n][r], 0.f);
          out[(size_t)row*8192 + col] = __expf(-d)*inv + 1e-10f;
        }
      }
    }
  }
}

// ---------------- host launch ----------------
extern "C" void kernel_launch(void* const* d_in, const int* in_sizes, int n_in,
                              void* d_out, int out_size, void* d_ws, size_t ws_size,
                              hipStream_t stream)
{
  const float* xi = (const float*)d_in[0];   // [8192,512]
  const float* F  = (const float*)d_in[1];   // [8192,8192]
  const float* w1 = (const float*)d_in[2];   // [512,256]
  const float* w2 = (const float*)d_in[3];   // [256,64]
  float* out = (float*)d_out;
  float* emb_out = out;                      // 8192*64
  float* recons  = out + (size_t)8192*64;    // 8192*8192

  // F-bf16 lives in the recons region of d_out (scratch until k_dist<2>
  // overwrites every element of it at the end).
  unsigned short* Fb = (unsigned short*)recons;   // 134 MB of the 268 MB region

  char* ws = (char*)d_ws;
  size_t off = 0;
  auto alloc = [&](size_t bytes)->char*{ char* p = ws + off; off += (bytes + 255) & ~(size_t)255; return p; };
  unsigned short* w1t  = (unsigned short*)alloc((size_t)256*512*2);
  unsigned short* w2t  = (unsigned short*)alloc((size_t)64*256*2);
  unsigned short* xib  = (unsigned short*)alloc((size_t)8192*512*2);
  unsigned short* t1t  = (unsigned short*)alloc((size_t)256*8192*2);
  unsigned short* t2t  = (unsigned short*)alloc((size_t)64*8192*2);
  unsigned short* h    = (unsigned short*)alloc((size_t)8192*256*2);
  unsigned short* embb = (unsigned short*)alloc((size_t)8192*64*2);
  float* sq    = (float*)alloc((size_t)8192*4);
  char* zbase = ws + off;
  float* h_acc   = (float*)alloc((size_t)8192*256*4);
  float* emb_acc = (float*)alloc((size_t)8192*64*4);
  float* S       = (float*)alloc((size_t)8192*4);
  size_t zbytes = (size_t)((ws + off) - zbase);

  hipMemsetAsync(zbase, 0, zbytes, stream);

  // conversions
  k_cvt<<<dim3(2048),256,0,stream>>>(F,  Fb,  (long)8192*8192/4);
  k_cvt<<<dim3(2048),256,0,stream>>>(xi, xib, (long)8192*512/4);
  k_transpose_bf16<<<dim3((512*256+255)/256), 256, 0, stream>>>(w1, w1t, 512, 256);
  k_transpose_bf16<<<dim3((256*64+255)/256),  256, 0, stream>>>(w2, w2t, 256, 64);

  // G1: t1t[256,8192] = w1t[256,512] @ xib[8192,512]^T   (256 blocks)
  k_gemm<128,64,64,2,2,false><<<dim3(128,2,1),256,0,stream>>>(
      w1t, xib, t1t, 512, 512, 8192, 512);

  // G2: h_acc[8192,256] += Fb @ t1t^T  (BN=256 -> F read once; split-K=8, 512 blocks)
  k_gemm<128,256,32,2,4,true><<<dim3(1,64,8),512,0,stream>>>(
      Fb, t1t, h_acc, 8192, 8192, 256, 1024);

  k_relu_bf16<<<dim3(8192*256/4/256),256,0,stream>>>(h_acc, h, 8192*256/4);

  // G3: t2t[64,8192] = w2t[64,256] @ h[8192,256]^T   (128 blocks)
  k_gemm<64,64,64,2,2,false><<<dim3(128,1,1),256,0,stream>>>(
      w2t, h, t2t, 256, 256, 8192, 256);

  // G4: emb_acc[8192,64] += Fb @ t2t^T   (split-K=8, 512 blocks, BK=64)
  k_gemm<128,64,64,2,2,true><<<dim3(1,64,8),256,0,stream>>>(
      Fb, t2t, emb_acc, 8192, 8192, 64, 1024);

  k_emb_fin<<<dim3(8192*64/256),256,0,stream>>>(emb_acc, emb_out, embb, sq);

  k_dist<1><<<dim3(64,64),256,0,stream>>>(embb, sq, S, recons);
  k_dist<2><<<dim3(64,64),256,0,stream>>>(embb, sq, S, recons);
}